// Round 15
// baseline (47.547 us; speedup 1.0000x reference)
//
#include <hip/hip_runtime.h>
#include <math.h>

// WaveletLayerND: fused mexican-hat wavelet + grouped 3x3 conv (kernel 1),
// then 1x1 channel mix (kernel 2). B=4, O=I=32, H=W=128, fp32 throughout.
//
// Round 15: per-wave LDS double-buffer, ZERO in-loop barriers.
// Evidence so far: register prefetch gets sunk by the allocator (r12,
// VGPR=68); global_load_lds can't be sunk (no VGPR dest) but r14 paired it
// with per-chunk vmcnt(0)+16-wave __syncthreads -> convoy ate the gain.
// Here each wave stages ITS OWN next channel into ITS OWN LDS region:
// producer == consumer, so a counted s_waitcnt vmcnt(5) replaces barriers.
// Loop: issue 5 gload_lds for ch c+1 (fire-and-forget) -> vmcnt(5) (waits
// only ch c's loads, covered by a full channel of compute) -> compute ch c.
// Block: 256 thr = 4 waves = one o, i split 4-way (r10 layout, 2048 blocks).
// LDS: 4 waves x 2 bufs x 1280 f = 40 KB -> 4 blocks/CU, 16 waves/CU.
// Compute: r10 tap basis (TL/TC/TR += w*psi; halo = 2 bperm/row, epilogue).
// Natural VGPR; NO launch_bounds min-arg (r3/r4/r7: caps below natural
// footprint spill acc to scratch).

#define RSTRIP 8   // output rows per wave

typedef float v2f __attribute__((ext_vector_type(2)));

static __device__ __forceinline__ v2f vfma(float w, v2f a, v2f c) {
  return __builtin_elementwise_fma(a, (v2f){w, w}, c);
}
static __device__ __forceinline__ float bperm(int addr, float v) {
  return __int_as_float(__builtin_amdgcn_ds_bpermute(addr, __float_as_int(v)));
}
// psi((x-t)/s) scaled by m (= MH_C * row_validity):  m*(u-1)*exp(-u/2)
static __device__ __forceinline__ v2f psi2(v2f xv, float rs, float trs, float m) {
  const float NHL2E = -0.72134752044448170f; // -0.5 * log2(e)
  const v2f sx = __builtin_elementwise_fma(xv, (v2f){rs, rs}, (v2f){-trs, -trs});
  const v2f u  = sx * sx;
  v2f e;
  e.x = __builtin_amdgcn_exp2f(u.x * NHL2E);
  e.y = __builtin_amdgcn_exp2f(u.y * NHL2E);
  return __builtin_elementwise_fma(u, (v2f){m, m}, (v2f){-m, -m}) * e;
}
// async global->LDS, 16B/lane: LDS dest = wave-uniform base + lane*16,
// global src per-lane (m104 caveat respected: linear LDS dest).
static __device__ __forceinline__ void gload_lds16(const float* g, float* l) {
  __builtin_amdgcn_global_load_lds(
      (const __attribute__((address_space(1))) void*)g,
      (__attribute__((address_space(3))) void*)l, 16, 0, 0);
}

__global__ __launch_bounds__(256) void wavelet_grouped_conv(
    const float* __restrict__ x,      // (B, I, H, W)
    const float* __restrict__ scale,  // (O*I)
    const float* __restrict__ trans,  // (O*I)
    const float* __restrict__ wconv,  // (O, I, 3, 3)
    float* __restrict__ y,            // (B, O, H, W) workspace
    float mhc)
{
  const int tid   = threadIdx.x;
  const int lane  = tid & 63;
  const int iq    = tid >> 6;          // 0..3: which i-quarter this wave owns
  const int strip = blockIdx.x;        // 0..15
  const int o     = blockIdx.y;        // 0..31
  const int b     = blockIdx.z;        // 0..3
  const int r0    = strip * RSTRIP;
  const int c0    = lane << 1;         // this thread's two columns

  // bpermute byte-addresses: lane-1 / lane+1 (mod 64) — epilogue only
  const int a_up = ((lane + 63) & 63) << 2;
  const int a_dn = ((lane +  1) & 63) << 2;
  const bool lane0  = (lane == 0);
  const bool lane63 = (lane == 63);

  // row validity folded into the psi prefactor (0 == the conv's zero pad)
  const float mhc_m1 = (r0 > 0)       ? mhc : 0.f;   // input row r0-1
  const float mhc_p8 = (r0 + 8 < 128) ? mhc : 0.f;   // input row r0+8

  // per-tap accumulators: out[c] = TL[c-1] + TC[c] + TR[c+1] (combined at end)
  v2f TL[RSTRIP], TC[RSTRIP], TR[RSTRIP];
#pragma unroll
  for (int r = 0; r < RSTRIP; ++r) {
    TL[r] = (v2f){0.f, 0.f}; TC[r] = (v2f){0.f, 0.f}; TR[r] = (v2f){0.f, 0.f};
  }

  const float* xb = x + (size_t)b * 32 * 128 * 128;

  // per-wave LDS double buffer: 10 rows x 128 f per buffer
  __shared__ float stage[4][2][1280];   // 40 KB
  float* base0 = &stage[iq][0][0];      // wave-uniform

  // per-lane global offsets for the 5 row-pair slices (clamped rows; clamp
  // only bites at image edges, data is zeroed later via mhc_m1/mhc_p8)
  int goff[5];
#pragma unroll
  for (int k = 0; k < 5; ++k) {
    int row = r0 - 1 + 2 * k + (lane >> 5);
    row = min(max(row, 0), 127);
    goff[k] = row * 128 + (lane & 31) * 4;
  }

  // stage channel K of this wave's quarter into bufp (5 x 1024B slices)
#define STAGE_CH(bufp, K)                                          \
  {                                                                \
    const float* xch = xb + (size_t)(iq * 8 + (K)) * 16384;        \
    _Pragma("unroll")                                              \
    for (int k = 0; k < 5; ++k)                                    \
      gload_lds16(xch + goff[k], (bufp) + k * 256);                \
  }

  // compute channel K (tap basis) from bufp
#define COMPUTE(bufp, K)                                                    \
  {                                                                         \
    const int oi = __builtin_amdgcn_readfirstlane(o * 32 + iq * 8 + (K));   \
    const float rs  = 1.0f / scale[oi];                                     \
    const float trs = trans[oi] * rs;                                       \
    const float* wp = wconv + oi * 9;                                       \
    const float w00 = wp[0], w01 = wp[1], w02 = wp[2];                      \
    const float w10 = wp[3], w11 = wp[4], w12 = wp[5];                      \
    const float w20 = wp[6], w21 = wp[7], w22 = wp[8];                      \
    _Pragma("unroll")                                                       \
    for (int j = 0; j < RSTRIP + 2; ++j) {                                  \
      const float mj = (j == 0) ? mhc_m1 : (j == RSTRIP + 1) ? mhc_p8 : mhc;\
      const v2f p = psi2(*(const v2f*)((bufp) + j * 128 + c0), rs, trs, mj);\
      if (j <= RSTRIP - 1) {                                                \
        TL[j] = vfma(w00, p, TL[j]);                                        \
        TC[j] = vfma(w01, p, TC[j]);                                        \
        TR[j] = vfma(w02, p, TR[j]);                                        \
      }                                                                     \
      if (j >= 1 && j <= RSTRIP) {                                          \
        TL[j-1] = vfma(w10, p, TL[j-1]);                                    \
        TC[j-1] = vfma(w11, p, TC[j-1]);                                    \
        TR[j-1] = vfma(w12, p, TR[j-1]);                                    \
      }                                                                     \
      if (j >= 2) {                                                         \
        TL[j-2] = vfma(w20, p, TL[j-2]);                                    \
        TC[j-2] = vfma(w21, p, TC[j-2]);                                    \
        TR[j-2] = vfma(w22, p, TR[j-2]);                                    \
      }                                                                     \
    }                                                                       \
  }

  STAGE_CH(base0, 0)

#pragma unroll 1
  for (int c = 0; c < 8; ++c) {
    float* cur = base0 + (c & 1) * 1280;
    float* nxt = base0 + ((c + 1) & 1) * 1280;
    __builtin_amdgcn_sched_barrier(0);
    if (c < 7) {
      STAGE_CH(nxt, c + 1)                          // fire-and-forget
      asm volatile("s_waitcnt vmcnt(5)" ::: "memory");  // ch c's 5 done
    } else {
      asm volatile("s_waitcnt vmcnt(0)" ::: "memory");
    }
    __builtin_amdgcn_sched_barrier(0);
    COMPUTE(cur, c)
  }
#undef COMPUTE
#undef STAGE_CH

  // horizontal combine: out[c0]   = TL[c0-1] + TC[c0]   + TR[c0+1]
  //                     out[c0+1] = TL[c0]   + TC[c0+1] + TR[c0+2]
  v2f acc[RSTRIP];
#pragma unroll
  for (int r = 0; r < RSTRIP; ++r) {
    float pl = bperm(a_up, TL[r].y);
    float pr = bperm(a_dn, TR[r].x);
    if (lane0)  pl = 0.f;
    if (lane63) pr = 0.f;
    v2f v;
    v.x = pl      + TC[r].x + TR[r].y;
    v.y = TL[r].x + TC[r].y + pr;
    acc[r] = v;
  }

  // i-quarter reduce through LDS; overlay the stage area (12 KB needed).
  // Barrier 1: all waves done with their stage buffers before overlay write.
  __syncthreads();
  float* red = &stage[0][0][0];
  if (iq != 0) {
#pragma unroll
    for (int r = 0; r < RSTRIP; ++r)
      *(v2f*)(red + (((iq - 1) * RSTRIP + r) * 64 + lane) * 2) = acc[r];
  }
  __syncthreads();
  if (iq == 0) {
    float* yb = y + (((size_t)b * 32 + o) * 128 + r0) * 128 + c0;
#pragma unroll
    for (int r = 0; r < RSTRIP; ++r) {
      const v2f v = acc[r]
        + *(const v2f*)(red + ((0 * RSTRIP + r) * 64 + lane) * 2)
        + *(const v2f*)(red + ((1 * RSTRIP + r) * 64 + lane) * 2)
        + *(const v2f*)(red + ((2 * RSTRIP + r) * 64 + lane) * 2);
      *(v2f*)(yb + (size_t)r * 128) = v;
    }
  }
}

__global__ __launch_bounds__(256) void mix1x1(
    const float* __restrict__ y,    // (B, O, H*W)
    const float* __restrict__ fw,   // (O_out, O_in)
    float* __restrict__ out)        // (B, O, H*W)
{
  const int px = blockIdx.x * 256 + threadIdx.x;  // 0..16383
  const int b  = blockIdx.y;
  const float* yb = y + (size_t)b * 32 * 16384 + px;
  float v[32];
#pragma unroll
  for (int o = 0; o < 32; ++o) v[o] = yb[(size_t)o * 16384];
  float* ob = out + (size_t)b * 32 * 16384 + px;
#pragma unroll
  for (int p = 0; p < 32; ++p) {
    float a = 0.f;
#pragma unroll
    for (int o = 0; o < 32; ++o) a = fmaf(fw[p * 32 + o], v[o], a);
    ob[(size_t)p * 16384] = a;
  }
}

extern "C" void kernel_launch(void* const* d_in, const int* in_sizes, int n_in,
                              void* d_out, int out_size, void* d_ws, size_t ws_size,
                              hipStream_t stream) {
  const float* x     = (const float*)d_in[0];
  const float* scale = (const float*)d_in[1];
  const float* trans = (const float*)d_in[2];
  const float* wconv = (const float*)d_in[3];
  const float* fw    = (const float*)d_in[4];
  float* out = (float*)d_out;
  float* y   = (float*)d_ws;   // 4*32*128*128 floats = 8.39 MB

  const float mhc = (float)(2.0 / (sqrt(3.0) * pow(M_PI, 0.25)));

  dim3 g1(16, 32, 4);            // (strip, o, b) = 2048 blocks x 256 thr
  wavelet_grouped_conv<<<g1, 256, 0, stream>>>(x, scale, trans, wconv, y, mhc);

  dim3 g2(16384 / 256, 4);       // (pixel tiles, b)
  mix1x1<<<g2, 256, 0, stream>>>(y, fw, out);
}

// Round 16
// 47.144 us; speedup vs baseline: 1.0085x; 1.0085x over previous
//
#include <hip/hip_runtime.h>
#include <math.h>

// WaveletLayerND: fused mexican-hat wavelet + grouped 3x3 conv (kernel 1),
// then 1x1 channel mix (kernel 2). B=4, O=I=32, H=W=128, fp32 throughout.
//
// Round 16: VGPR-tier push. Re-derived model: v_pk_fma_f32 is HALF-RATE on
// CDNA4 (fp32 peak 157TF = 1 FMA/lane/cy; pk occupies SIMD 4cy) -> kernel is
// ~60% issue-bound, and VGPR 68-76 puts every round since r8 in the 4-wave/
// SIMD tier (waves halve at 64/128, m69) with ~2-3 resident. Fix: natural
// VGPR <= 64 (8-wave tier) by shrinking the accumulators: RSTRIP=4 -> 
// TL/TC/TR = 24 VGPR (was 48). Halo cost 1.5x on psi only (+9% work), paid
// for by ~1.5x issue utilization. psi cut to 5 issues: v=fma(x,rsc,-trsc)
// (rsc=c/s, c^2=0.5*log2e), w=-v*v, psi=fma(w,K1,K2)*exp2(w), K1/K2 global
// consts with edge-row variants folding the zero-pad. No in-loop barriers,
// plain loads, 8-wave TLP hides L2. NO launch_bounds min-arg (r3/4/7).

#define RSTRIP 4   // output rows per wave

typedef float v2f __attribute__((ext_vector_type(2)));

static __device__ __forceinline__ v2f vfma(float w, v2f a, v2f c) {
  return __builtin_elementwise_fma(a, (v2f){w, w}, c);
}
static __device__ __forceinline__ float bperm(int addr, float v) {
  return __int_as_float(__builtin_amdgcn_ds_bpermute(addr, __float_as_int(v)));
}

__global__ __launch_bounds__(256) void wavelet_grouped_conv(
    const float* __restrict__ x,      // (B, I, H, W)
    const float* __restrict__ scale,  // (O*I)
    const float* __restrict__ trans,  // (O*I)
    const float* __restrict__ wconv,  // (O, I, 3, 3)
    float* __restrict__ y,            // (B, O, H, W) workspace
    float mhc)
{
  const int tid   = threadIdx.x;
  const int lane  = tid & 63;
  const int wv    = tid >> 6;          // 0..3
  const int o_idx = wv & 1;            // which o of the block's pair
  const int ihalf = wv >> 1;           // 0: ch 0..15, 1: ch 16..31
  const int strip = blockIdx.x;        // 0..31
  const int op    = blockIdx.y;        // 0..15
  const int b     = blockIdx.z;        // 0..3
  const int o     = op * 2 + o_idx;
  const int r0    = strip * RSTRIP;
  const int c0    = lane << 1;         // this thread's two columns

  // bpermute byte-addresses: lane-1 / lane+1 (mod 64) — epilogue only
  const int a_up = ((lane + 63) & 63) << 2;
  const int a_dn = ((lane +  1) & 63) << 2;
  const bool lane0  = (lane == 0);
  const bool lane63 = (lane == 63);

  // psi(v) = fma(w,K1,K2)*exp2(w), w = -(CC*sx)^2, CC^2 = 0.5*log2(e)
  const float C2 = 0.72134752044448170f;
  const float CC = 0.84932214f;
  const float K1 = -mhc / C2;
  const float K2 = -mhc;
  // edge-row variants fold the conv's zero padding (psi -> 0)
  const float rv0 = (r0 > 0) ? 1.f : 0.f;            // input row r0-1
  const float rv5 = (r0 + RSTRIP < 128) ? 1.f : 0.f; // input row r0+4
  const float K1a = K1 * rv0, K2a = K2 * rv0;
  const float K1b = K1 * rv5, K2b = K2 * rv5;

  // per-tap accumulators: out[c] = TL[c-1] + TC[c] + TR[c+1] (combined at end)
  v2f TL[RSTRIP], TC[RSTRIP], TR[RSTRIP];
#pragma unroll
  for (int r = 0; r < RSTRIP; ++r) {
    TL[r] = (v2f){0.f, 0.f}; TC[r] = (v2f){0.f, 0.f}; TR[r] = (v2f){0.f, 0.f};
  }

  // per-lane clamped element offsets for the 6 rows (computed once)
  int off[RSTRIP + 2];
#pragma unroll
  for (int j = 0; j < RSTRIP + 2; ++j) {
    const int row = min(max(r0 + j - 1, 0), 127);
    off[j] = row * 128 + c0;
  }

  const float* xb = x + (size_t)b * 32 * 16384;

#pragma unroll 1
  for (int ci = 0; ci < 16; ++ci) {
    const int ch = ihalf * 16 + ci;                       // wave-uniform
    const int oi = __builtin_amdgcn_readfirstlane(o * 32 + ch);
    const float rsc  = CC / scale[oi];
    const float trsc = trans[oi] * rsc;
    const float* wp = wconv + oi * 9;
    const float w00 = wp[0], w01 = wp[1], w02 = wp[2];
    const float w10 = wp[3], w11 = wp[4], w12 = wp[5];
    const float w20 = wp[6], w21 = wp[7], w22 = wp[8];
    const float* chb = xb + (size_t)ch * 16384;

    v2f xr[RSTRIP + 2];
#pragma unroll
    for (int j = 0; j < RSTRIP + 2; ++j)
      xr[j] = *(const v2f*)(chb + off[j]);

#pragma unroll
    for (int j = 0; j < RSTRIP + 2; ++j) {
      const float k1 = (j == 0) ? K1a : (j == RSTRIP + 1) ? K1b : K1;
      const float k2 = (j == 0) ? K2a : (j == RSTRIP + 1) ? K2b : K2;
      const v2f v = __builtin_elementwise_fma(xr[j], (v2f){rsc, rsc},
                                              (v2f){-trsc, -trsc});
      const v2f wq = -(v * v);
      v2f e;
      e.x = __builtin_amdgcn_exp2f(wq.x);
      e.y = __builtin_amdgcn_exp2f(wq.y);
      const v2f p = __builtin_elementwise_fma(wq, (v2f){k1, k1},
                                              (v2f){k2, k2}) * e;
      // input row ir=r0+j-1 feeds out rows t=j (w0x), j-1 (w1x), j-2 (w2x)
      if (j <= RSTRIP - 1) {
        TL[j] = vfma(w00, p, TL[j]);
        TC[j] = vfma(w01, p, TC[j]);
        TR[j] = vfma(w02, p, TR[j]);
      }
      if (j >= 1 && j <= RSTRIP) {
        TL[j-1] = vfma(w10, p, TL[j-1]);
        TC[j-1] = vfma(w11, p, TC[j-1]);
        TR[j-1] = vfma(w12, p, TR[j-1]);
      }
      if (j >= 2) {
        TL[j-2] = vfma(w20, p, TL[j-2]);
        TC[j-2] = vfma(w21, p, TC[j-2]);
        TR[j-2] = vfma(w22, p, TR[j-2]);
      }
    }
  }

  // horizontal combine: out[c0]   = TL[c0-1] + TC[c0]   + TR[c0+1]
  //                     out[c0+1] = TL[c0]   + TC[c0+1] + TR[c0+2]
  v2f acc[RSTRIP];
#pragma unroll
  for (int r = 0; r < RSTRIP; ++r) {
    float pl = bperm(a_up, TL[r].y);
    float pr = bperm(a_dn, TR[r].x);
    if (lane0)  pl = 0.f;
    if (lane63) pr = 0.f;
    v2f v;
    v.x = pl      + TC[r].x + TR[r].y;
    v.y = TL[r].x + TC[r].y + pr;
    acc[r] = v;
  }

  // 2-way i-half reduce through LDS (lane-major; b64 2-way is free)
  __shared__ v2f red[2][RSTRIP][64];   // 4 KB
  if (ihalf == 1) {
#pragma unroll
    for (int r = 0; r < RSTRIP; ++r) red[o_idx][r][lane] = acc[r];
  }
  __syncthreads();
  if (ihalf == 0) {
    float* yb = y + (((size_t)b * 32 + o) * 128 + r0) * 128 + c0;
#pragma unroll
    for (int r = 0; r < RSTRIP; ++r) {
      const v2f v = acc[r] + red[o_idx][r][lane];
      *(v2f*)(yb + (size_t)r * 128) = v;
    }
  }
}

__global__ __launch_bounds__(256) void mix1x1(
    const float* __restrict__ y,    // (B, O, H*W)
    const float* __restrict__ fw,   // (O_out, O_in)
    float* __restrict__ out)        // (B, O, H*W)
{
  const int px = blockIdx.x * 256 + threadIdx.x;  // 0..16383
  const int b  = blockIdx.y;
  const float* yb = y + (size_t)b * 32 * 16384 + px;
  float v[32];
#pragma unroll
  for (int o = 0; o < 32; ++o) v[o] = yb[(size_t)o * 16384];
  float* ob = out + (size_t)b * 32 * 16384 + px;
#pragma unroll
  for (int p = 0; p < 32; ++p) {
    float a = 0.f;
#pragma unroll
    for (int o = 0; o < 32; ++o) a = fmaf(fw[p * 32 + o], v[o], a);
    ob[(size_t)p * 16384] = a;
  }
}

extern "C" void kernel_launch(void* const* d_in, const int* in_sizes, int n_in,
                              void* d_out, int out_size, void* d_ws, size_t ws_size,
                              hipStream_t stream) {
  const float* x     = (const float*)d_in[0];
  const float* scale = (const float*)d_in[1];
  const float* trans = (const float*)d_in[2];
  const float* wconv = (const float*)d_in[3];
  const float* fw    = (const float*)d_in[4];
  float* out = (float*)d_out;
  float* y   = (float*)d_ws;   // 4*32*128*128 floats = 8.39 MB

  const float mhc = (float)(2.0 / (sqrt(3.0) * pow(M_PI, 0.25)));

  dim3 g1(128 / RSTRIP, 16, 4);  // (strip, o-pair, b) = 2048 blocks x 256 thr
  wavelet_grouped_conv<<<g1, 256, 0, stream>>>(x, scale, trans, wconv, y, mhc);

  dim3 g2(16384 / 256, 4);       // (pixel tiles, b)
  mix1x1<<<g2, 256, 0, stream>>>(y, fw, out);
}